// Round 12
// baseline (142.026 us; speedup 1.0000x reference)
//
#include <hip/hip_runtime.h>
#include <hip/hip_bf16.h>
#include <math.h>

#define BATCH 32768

typedef __attribute__((ext_vector_type(8))) short short8v;  // 8 bf16 (MFMA A/B frag)
typedef __attribute__((ext_vector_type(4))) float f32x4;
typedef __attribute__((ext_vector_type(2))) float f32x2;
typedef unsigned short u16;
typedef unsigned char u8;

#define MFMA16 __builtin_amdgcn_mfma_f32_16x16x32_bf16

// ---- LDS map (bytes), 80 KiB exactly -> 2 blocks/CU ----
// [0,32768): 4 rotating T slice bufs (8 KB each, bf16 hi only)
//            after i-loop: PRE merge scratch f32[NV][64k][64b]; then OSTG (pass C)
#define TILE_AB 32768   // f32x2 [f 64][b 64]: (e1,er) -> (a1,ar); read [i][b], write [k][b]
#define TILE_C  65536   // f32   [f 64][b 64]: p -> c2
#define SMB     81920

// ---- d_ws map ----
// T tensor t at t*512KiB: 64 slices x 8KB, each an exact LDS image (hi only):
//   [kt 4][lr 16][pc 8][16B], pc = (j>>3) ^ (lr&7)
#define WS_T(t) ((size_t)(t)*524288)
#define WS_W    1572864 // W1h, W1l, W2h, W2l: 4 x 8192 B (bf16 [k][64] linear)

static __device__ __forceinline__ u16 f2bf(float x) {
    __hip_bfloat16 h = __float2bfloat16(x);
    return *reinterpret_cast<u16*>(&h);
}
static __device__ __forceinline__ float bf2f(u16 v) {
    __hip_bfloat16 h = *reinterpret_cast<__hip_bfloat16*>(&v);
    return __bfloat162float(h);
}

// ============================ pre-split kernel ============================
__global__ void presplit_kernel(const float* __restrict__ T1, const float* __restrict__ T2,
                                const float* __restrict__ T3, const float* __restrict__ W,
                                u8* __restrict__ ws)
{
    const int idx = blockIdx.x * 256 + threadIdx.x;
    const int NT = 3 * 262144;
    if (idx < NT) {
        const int t = idx >> 18;
        const int r = idx & 262143;                 // k*4096 + i*64 + j
        const int k = r >> 12, i = (r >> 6) & 63, j = r & 63;
        const float* Ts = (t == 0) ? T1 : (t == 1) ? T2 : T3;
        const int kt = k >> 4, klr = k & 15;
        const int pc = (j >> 3) ^ (klr & 7);        // bank-spreading chunk swizzle
        const size_t base = WS_T(t) + (size_t)i * 8192 + kt * 2048 + klr * 128
                          + pc * 16 + (j & 7) * 2;
        *(u16*)(ws + base) = f2bf(Ts[r]);           // hi plane only
    } else if (idx < NT + 16384) {
        const int r = idx - NT;
        const int plane = r >> 12, k = (r >> 6) & 63, j = r & 63;  // W1h,W1l,W2h,W2l
        const int half = plane >> 1, lo = plane & 1;
        const float x = W[k * 128 + half * 64 + j];
        const u16 hh = f2bf(x);
        const u16 v = lo ? f2bf(x - bf2f(hh)) : hh;
        *(u16*)(ws + WS_W + (size_t)plane * 8192 + (k * 64 + j) * 2) = v;
    }
}

// ============================ device helpers ============================
__device__ __forceinline__ void stage16(const void* g, void* l) {
    __builtin_amdgcn_global_load_lds((const __attribute__((address_space(1))) unsigned int*)g,
                                     (__attribute__((address_space(3))) unsigned int*)l, 16, 0, 0);
}
// each wave stages its 1KB of an 8KB slice (linear dest; swizzle baked into ws)
__device__ __forceinline__ void stage_slice(u8* sm, const u8* slice, int buf, int w, int l) {
    stage16(slice + w * 1024 + l * 16, sm + buf * 8192 + w * 1024);
}

struct Frag2 { short8v h, l; };
__device__ __forceinline__ Frag2 split8(const float* __restrict__ src) {
    Frag2 f;
#pragma unroll
    for (int e = 0; e < 8; ++e) {
        const float x = src[e];
        const u16 h = f2bf(x);
        f.h[e] = (short)h;
        f.l[e] = (short)f2bf(x - bf2f(h));
    }
    return f;
}
// gather 8 consecutive f at fixed b from mono f32 [f][b] tile (broadcast: free)
__device__ __forceinline__ Frag2 gather_c(const u8* sm, int b, int f0) {
    float tmp[8];
#pragma unroll
    for (int e = 0; e < 8; ++e)
        tmp[e] = *(const float*)(sm + TILE_C + (f0 + e) * 256 + b * 4);
    return split8(tmp);
}
// gather both variants from the interleaved f32x2 [f][b] tile
__device__ __forceinline__ void gather_ab(const u8* sm, int b, int f0, Frag2& fa, Frag2& fb) {
    float t0[8], t1[8];
#pragma unroll
    for (int e = 0; e < 8; ++e) {
        const f32x2 v = *(const f32x2*)(sm + TILE_AB + (size_t)(f0 + e) * 512 + b * 8);
        t0[e] = v.x; t1[e] = v.y;
    }
    fa = split8(t0); fb = split8(t1);
}
__device__ __forceinline__ f32x4 mfma3(short8v Ah, short8v Al, short8v Bh, short8v Bl, f32x4 acc) {
    acc = MFMA16(Ah, Bh, acc, 0, 0, 0);
    acc = MFMA16(Ah, Bl, acc, 0, 0, 0);
    acc = MFMA16(Al, Bh, acc, 0, 0, 0);
    return acc;
}

// ============================ fused pass ============================
// Shared-S: per i, S_i[k,b] = sum_j T[k,i,j] c[b,j] via 2-term MFMA (T bf16-hi, c hi/lo;
// jh splits the j/K dim); bil_v[k,b] += a_v[b,i] * S_i (exact f32 scalars).
// ff jh-split (full hi/lo precision): jh0 adds W2.c + bias, jh1 adds W1.a_v.
// MODE 0: {a1,ar} = ntn({e1,er}, p, T1) -> TILE_AB
// MODE 1: c2 = ntn(p, e2, T2)           -> TILE_C
// MODE 2: {u,ur} = ntn({a1,ar}, c2, T3) -> global out
template<int MODE>
__device__ void pass_run(u8* sm, const u8* __restrict__ ws,
                         const float* __restrict__ gC, const float* __restrict__ gA0,
                         const float* __restrict__ gA1,
                         const float* __restrict__ bias, float* __restrict__ outg,
                         int B0, int w, int kt, int jh, int l, int lr, int lq, int tid)
{
    constexpr int NV = (MODE == 1) ? 1 : 2;
    const u8* tws = ws + WS_T(MODE);

    // prologue: 3 slices in flight before the ff work
    stage_slice(sm, tws,                    0, w, l);
    stage_slice(sm, tws + (size_t)1 * 8192, 1, w, l);
    stage_slice(sm, tws + (size_t)2 * 8192, 2, w, l);

    // ---------- c-side B-frags for the i-loop (own jh half, static) ----------
    short8v Bh[4], Bl[4];
#pragma unroll
    for (int nt = 0; nt < 4; ++nt) {
        const int b = nt * 16 + lr;
        Frag2 f;
        if (MODE < 2) f = split8(gC + (size_t)(B0 + b) * 64 + jh * 32 + lq * 8);
        else          f = gather_c(sm, b, jh * 32 + lq * 8);
        Bh[nt] = f.h; Bl[nt] = f.l;
    }

    // ---------- ff init (jh-split) ----------
    f32x4 bil[NV][4];
    {
        const u16* Wp = (const u16*)(ws + WS_W);
        if (jh == 0) {                              // W2 . c + bias (shared by the pair)
            short8v w2h[2], w2l[2];
#pragma unroll
            for (int h = 0; h < 2; ++h) {
                const int off = (kt * 16 + lr) * 64 + h * 32 + lq * 8;
                w2h[h] = *(const short8v*)(Wp + 8192 + off);
                w2l[h] = *(const short8v*)(Wp + 12288 + off);
            }
            const f32x4 bv4 = *(const f32x4*)(bias + kt * 16 + lq * 4);
#pragma unroll
            for (int nt = 0; nt < 4; ++nt) {
                const int b = nt * 16 + lr;
                f32x4 s = {0.f, 0.f, 0.f, 0.f};
#pragma unroll
                for (int h = 0; h < 2; ++h) {
                    Frag2 fc;
                    if (MODE < 2) fc = split8(gC + (size_t)(B0 + b) * 64 + h * 32 + lq * 8);
                    else          fc = gather_c(sm, b, h * 32 + lq * 8);
                    s = mfma3(w2h[h], w2l[h], fc.h, fc.l, s);
                }
#pragma unroll
                for (int v = 0; v < NV; ++v)
#pragma unroll
                for (int rg = 0; rg < 4; ++rg) bil[v][nt][rg] = s[rg] + bv4[rg];
            }
        } else {                                    // W1 . a_v
            short8v w1h[2], w1l[2];
#pragma unroll
            for (int h = 0; h < 2; ++h) {
                const int off = (kt * 16 + lr) * 64 + h * 32 + lq * 8;
                w1h[h] = *(const short8v*)(Wp + off);
                w1l[h] = *(const short8v*)(Wp + 4096 + off);
            }
#pragma unroll
            for (int nt = 0; nt < 4; ++nt) {
                const int b = nt * 16 + lr;
                f32x4 sv0 = {0.f, 0.f, 0.f, 0.f};
                f32x4 sv1 = {0.f, 0.f, 0.f, 0.f};
#pragma unroll
                for (int h = 0; h < 2; ++h) {
                    Frag2 fa, fb;
                    if (MODE == 0) {
                        fa = split8(gA0 + (size_t)(B0 + b) * 64 + h * 32 + lq * 8);
                        fb = split8(gA1 + (size_t)(B0 + b) * 64 + h * 32 + lq * 8);
                    } else if (MODE == 1) {
                        fa = split8(gA0 + (size_t)(B0 + b) * 64 + h * 32 + lq * 8);
                    } else {
                        gather_ab(sm, b, h * 32 + lq * 8, fa, fb);
                    }
                    sv0 = mfma3(w1h[h], w1l[h], fa.h, fa.l, sv0);
                    if (NV == 2) sv1 = mfma3(w1h[h], w1l[h], fb.h, fb.l, sv1);
                }
                bil[0][nt] = sv0;
                if (NV == 2) bil[1][nt] = sv1;
            }
        }
    }

    // ---------- i-loop: 4-buf rotation, counted vmcnt, sv loads overlap barrier ----------
    const int tswz = kt * 2048 + lr * 128 + (((jh * 4 + lq) ^ (lr & 7)) << 4);
    const f32x4 ZERO4 = {0.f, 0.f, 0.f, 0.f};       // persistent MFMA C-seed

#define STEP(I, VMN, DOSTG) do {                                                           \
    f32x2 sv[4];                                                                           \
    _Pragma("unroll") for (int nt = 0; nt < 4; ++nt) {                                     \
        if (MODE == 1) sv[nt].x = *(const float*)(sm + TILE_C + (I) * 256 + nt * 64 + lr * 4); \
        else sv[nt] = *(const f32x2*)(sm + TILE_AB + (I) * 512 + nt * 128 + lr * 8);       \
    }                                                                                      \
    asm volatile("s_waitcnt vmcnt(" #VMN ")" ::: "memory");                                \
    __builtin_amdgcn_sched_barrier(0);                                                     \
    __builtin_amdgcn_s_barrier();                                                          \
    __builtin_amdgcn_sched_barrier(0);                                                     \
    if (DOSTG) stage_slice(sm, tws + (size_t)((I) + 3) * 8192, ((I) + 3) & 3, w, l);       \
    const u8* tb_ = sm + ((I) & 3) * 8192 + tswz;                                          \
    const short8v Th_ = *(const short8v*)tb_;                                              \
    f32x4 S_[4];                                                                           \
    __builtin_amdgcn_s_setprio(1);                                                         \
    _Pragma("unroll") for (int nt = 0; nt < 4; ++nt) {                                     \
        f32x4 z_ = MFMA16(Th_, Bh[nt], ZERO4, 0, 0, 0);                                    \
        S_[nt] = MFMA16(Th_, Bl[nt], z_, 0, 0, 0);                                         \
    }                                                                                      \
    __builtin_amdgcn_s_setprio(0);                                                         \
    _Pragma("unroll") for (int nt = 0; nt < 4; ++nt)                                       \
    _Pragma("unroll") for (int rg = 0; rg < 4; ++rg) {                                     \
        bil[0][nt][rg] += sv[nt].x * S_[nt][rg];                                           \
        if (NV == 2) bil[1][nt][rg] += sv[nt].y * S_[nt][rg];                              \
    }                                                                                      \
} while (0)

#pragma unroll 4
    for (int i = 0; i < 60; ++i) STEP(i, 2, true);
    STEP(60, 2, true);                              // stages slice 63
    STEP(61, 2, false);
    STEP(62, 1, false);
    STEP(63, 0, false);
#undef STEP

    // ---------- jh merge (once per pass) + tanh + store ----------
    __syncthreads();                                // stage bufs dead -> PRE
    float* PRE = (float*)sm;                        // [NV][64 k][64 b] f32
    if (jh == 1) {
#pragma unroll
        for (int v = 0; v < NV; ++v)
#pragma unroll
        for (int nt = 0; nt < 4; ++nt)
#pragma unroll
        for (int rg = 0; rg < 4; ++rg)
            PRE[v * 4096 + (kt * 16 + lq * 4 + rg) * 64 + nt * 16 + lr] = bil[v][nt][rg];
    }
    __syncthreads();

    if (MODE == 0) {
        if (jh == 0) {
#pragma unroll
            for (int nt = 0; nt < 4; ++nt) {
                const int b = nt * 16 + lr;
#pragma unroll
                for (int rg = 0; rg < 4; ++rg) {
                    const int k = kt * 16 + lq * 4 + rg;
                    f32x2 o;
                    o.x = tanhf(bil[0][nt][rg] + PRE[k * 64 + b]);
                    o.y = tanhf(bil[1][nt][rg] + PRE[4096 + k * 64 + b]);
                    *(f32x2*)(sm + TILE_AB + (size_t)k * 512 + b * 8) = o;
                }
            }
        }
        __syncthreads();
    } else if (MODE == 1) {
        if (jh == 0) {
#pragma unroll
            for (int nt = 0; nt < 4; ++nt) {
                const int b = nt * 16 + lr;
#pragma unroll
                for (int rg = 0; rg < 4; ++rg) {
                    const int k = kt * 16 + lq * 4 + rg;
                    *(float*)(sm + TILE_C + k * 256 + b * 4) =
                        tanhf(bil[0][nt][rg] + PRE[k * 64 + b]);
                }
            }
        }
        __syncthreads();
    } else {
        f32x2 ures[4][4];
        if (jh == 0) {
#pragma unroll
            for (int nt = 0; nt < 4; ++nt) {
                const int b = nt * 16 + lr;
#pragma unroll
                for (int rg = 0; rg < 4; ++rg) {
                    const int k = kt * 16 + lq * 4 + rg;
                    ures[nt][rg].x = tanhf(bil[0][nt][rg] + PRE[k * 64 + b]);
                    ures[nt][rg].y = tanhf(bil[1][nt][rg] + PRE[4096 + k * 64 + b]);
                }
            }
        }
        __syncthreads();                            // PRE reads done -> OSTG may overwrite
        if (jh == 0) {
#pragma unroll
            for (int nt = 0; nt < 4; ++nt) {
                const int b = nt * 16 + lr;
#pragma unroll
                for (int rg = 0; rg < 4; ++rg) {
                    const int k = kt * 16 + lq * 4 + rg;
                    *(f32x2*)(sm + b * 512 + (((k ^ b) & 63) << 3)) = ures[nt][rg];
                }
            }
        }
        __syncthreads();
        const int bq = tid >> 3, t = tid & 7;       // coalesced 64B per thread
        float o[16];
#pragma unroll
        for (int kk = 0; kk < 8; ++kk) {
            const int k = t * 8 + kk;
            const f32x2 pr = *(const f32x2*)(sm + bq * 512 + (((k ^ bq) & 63) << 3));
            o[kk * 2] = pr.x; o[kk * 2 + 1] = pr.y;
        }
        float* dst = outg + (size_t)(B0 + bq) * 128 + t * 16;
#pragma unroll
        for (int q = 0; q < 4; ++q) *(f32x4*)(dst + q * 4) = *(const f32x4*)(o + q * 4);
    }
}

__global__ __launch_bounds__(512, 4)
void ntn_main(const float* __restrict__ e1, const float* __restrict__ p,
              const float* __restrict__ e2, const float* __restrict__ er,
              const float* __restrict__ bias, const u8* __restrict__ ws,
              float* __restrict__ out)
{
    __shared__ __align__(16) u8 sm[SMB];
    const int tid = threadIdx.x;
    const int l = tid & 63;
    const int w = __builtin_amdgcn_readfirstlane(tid >> 6);
    const int kt = w & 3, jh = w >> 2;
    const int lr = l & 15, lq = l >> 4;
    const int B0 = blockIdx.x * 64;

    // fill tiles: AB = (e1, er) interleaved [f][b], C = p mono [f][b]
    {
        const int b = tid >> 3, f0 = (tid & 7) * 8;
        const size_t g = (size_t)(B0 + b) * 64 + f0;
        const f32x4 a0 = *(const f32x4*)(e1 + g), a1v = *(const f32x4*)(e1 + g + 4);
        const f32x4 r0 = *(const f32x4*)(er + g), r1v = *(const f32x4*)(er + g + 4);
        const f32x4 p0 = *(const f32x4*)(p + g),  p1v = *(const f32x4*)(p + g + 4);
#pragma unroll
        for (int e = 0; e < 4; ++e) {
            f32x2 v0; v0.x = a0[e]; v0.y = r0[e];
            *(f32x2*)(sm + TILE_AB + (size_t)(f0 + e) * 512 + b * 8) = v0;
            f32x2 v1; v1.x = a1v[e]; v1.y = r1v[e];
            *(f32x2*)(sm + TILE_AB + (size_t)(f0 + 4 + e) * 512 + b * 8) = v1;
            *(float*)(sm + TILE_C + (f0 + e) * 256 + b * 4) = p0[e];
            *(float*)(sm + TILE_C + (f0 + 4 + e) * 256 + b * 4) = p1v[e];
        }
    }
    __syncthreads();

    pass_run<0>(sm, ws, p,  e1, er,      bias, nullptr, B0, w, kt, jh, l, lr, lq, tid);
    pass_run<1>(sm, ws, e2, p,  nullptr, bias, nullptr, B0, w, kt, jh, l, lr, lq, tid);
    pass_run<2>(sm, ws, nullptr, nullptr, nullptr, bias, out, B0, w, kt, jh, l, lr, lq, tid);
}

extern "C" void kernel_launch(void* const* d_in, const int* in_sizes, int n_in,
                              void* d_out, int out_size, void* d_ws, size_t ws_size,
                              hipStream_t stream) {
    const float* e1   = (const float*)d_in[0];
    const float* p    = (const float*)d_in[1];
    const float* e2   = (const float*)d_in[2];
    const float* er   = (const float*)d_in[3];
    const float* T1   = (const float*)d_in[4];
    const float* T2   = (const float*)d_in[5];
    const float* T3   = (const float*)d_in[6];
    const float* W    = (const float*)d_in[7];
    const float* bias = (const float*)d_in[8];

    u8* ws = (u8*)d_ws;
    hipLaunchKernelGGL(presplit_kernel, dim3(3136), dim3(256), 0, stream, T1, T2, T3, W, ws);
    hipLaunchKernelGGL(ntn_main, dim3(BATCH / 64), dim3(512), 0, stream,
                       e1, p, e2, er, bias, (const u8*)ws, (float*)d_out);
}

// Round 13
// 139.233 us; speedup vs baseline: 1.0201x; 1.0201x over previous
//
#include <hip/hip_runtime.h>
#include <hip/hip_bf16.h>
#include <math.h>

#define BATCH 32768

typedef __attribute__((ext_vector_type(8))) short short8v;  // 8 bf16 (MFMA A/B frag)
typedef __attribute__((ext_vector_type(4))) float f32x4;
typedef __attribute__((ext_vector_type(2))) float f32x2;
typedef unsigned short u16;
typedef unsigned char u8;

#define MFMA16 __builtin_amdgcn_mfma_f32_16x16x32_bf16

// ---- LDS map (bytes), 80 KiB exactly -> 2 blocks/CU ----
// [0,32768): 4 rotating T slice bufs (8 KB each, bf16 hi only; buf = slice & 3)
//            after i-loop: PRE merge scratch f32[NV][64k][64b]; then OSTG (pass C)
#define TILE_AB 32768   // f32x2 [f 64][b 64]: (e1,er) -> (a1,ar); read [i][b], write [k][b]
#define TILE_C  65536   // f32   [f 64][b 64]: p -> c2
#define SMB     81920

// ---- d_ws map ----
// T tensor t at t*512KiB: 64 slices x 8KB, each an exact LDS image (hi only):
//   [kt 4][lr 16][pc 8][16B], pc = (j>>3) ^ (lr&7)
#define WS_T(t) ((size_t)(t)*524288)
#define WS_W    1572864 // W1h, W1l, W2h, W2l: 4 x 8192 B (bf16 [k][64] linear)

static __device__ __forceinline__ u16 f2bf(float x) {
    __hip_bfloat16 h = __float2bfloat16(x);
    return *reinterpret_cast<u16*>(&h);
}
static __device__ __forceinline__ float bf2f(u16 v) {
    __hip_bfloat16 h = *reinterpret_cast<__hip_bfloat16*>(&v);
    return __bfloat162float(h);
}

// ============================ pre-split kernel ============================
__global__ void presplit_kernel(const float* __restrict__ T1, const float* __restrict__ T2,
                                const float* __restrict__ T3, const float* __restrict__ W,
                                u8* __restrict__ ws)
{
    const int idx = blockIdx.x * 256 + threadIdx.x;
    const int NT = 3 * 262144;
    if (idx < NT) {
        const int t = idx >> 18;
        const int r = idx & 262143;                 // k*4096 + i*64 + j
        const int k = r >> 12, i = (r >> 6) & 63, j = r & 63;
        const float* Ts = (t == 0) ? T1 : (t == 1) ? T2 : T3;
        const int kt = k >> 4, klr = k & 15;
        const int pc = (j >> 3) ^ (klr & 7);        // bank-spreading chunk swizzle
        const size_t base = WS_T(t) + (size_t)i * 8192 + kt * 2048 + klr * 128
                          + pc * 16 + (j & 7) * 2;
        *(u16*)(ws + base) = f2bf(Ts[r]);           // hi plane only
    } else if (idx < NT + 16384) {
        const int r = idx - NT;
        const int plane = r >> 12, k = (r >> 6) & 63, j = r & 63;  // W1h,W1l,W2h,W2l
        const int half = plane >> 1, lo = plane & 1;
        const float x = W[k * 128 + half * 64 + j];
        const u16 hh = f2bf(x);
        const u16 v = lo ? f2bf(x - bf2f(hh)) : hh;
        *(u16*)(ws + WS_W + (size_t)plane * 8192 + (k * 64 + j) * 2) = v;
    }
}

// ============================ device helpers ============================
__device__ __forceinline__ void stage16(const void* g, void* l) {
    __builtin_amdgcn_global_load_lds((const __attribute__((address_space(1))) unsigned int*)g,
                                     (__attribute__((address_space(3))) unsigned int*)l, 16, 0, 0);
}
// each wave stages its 1KB of an 8KB slice (linear dest; swizzle baked into ws)
__device__ __forceinline__ void stage_slice(u8* sm, const u8* slice, int buf, int w, int l) {
    stage16(slice + w * 1024 + l * 16, sm + buf * 8192 + w * 1024);
}

struct Frag2 { short8v h, l; };
__device__ __forceinline__ Frag2 split8(const float* __restrict__ src) {
    Frag2 f;
#pragma unroll
    for (int e = 0; e < 8; ++e) {
        const float x = src[e];
        const u16 h = f2bf(x);
        f.h[e] = (short)h;
        f.l[e] = (short)f2bf(x - bf2f(h));
    }
    return f;
}
// gather 8 consecutive f at fixed b from mono f32 [f][b] tile (broadcast: free)
__device__ __forceinline__ Frag2 gather_c(const u8* sm, int b, int f0) {
    float tmp[8];
#pragma unroll
    for (int e = 0; e < 8; ++e)
        tmp[e] = *(const float*)(sm + TILE_C + (f0 + e) * 256 + b * 4);
    return split8(tmp);
}
// gather both variants from the interleaved f32x2 [f][b] tile
__device__ __forceinline__ void gather_ab(const u8* sm, int b, int f0, Frag2& fa, Frag2& fb) {
    float t0[8], t1[8];
#pragma unroll
    for (int e = 0; e < 8; ++e) {
        const f32x2 v = *(const f32x2*)(sm + TILE_AB + (size_t)(f0 + e) * 512 + b * 8);
        t0[e] = v.x; t1[e] = v.y;
    }
    fa = split8(t0); fb = split8(t1);
}
__device__ __forceinline__ f32x4 mfma3(short8v Ah, short8v Al, short8v Bh, short8v Bl, f32x4 acc) {
    acc = MFMA16(Ah, Bh, acc, 0, 0, 0);
    acc = MFMA16(Ah, Bl, acc, 0, 0, 0);
    acc = MFMA16(Al, Bh, acc, 0, 0, 0);
    return acc;
}

// ============================ fused pass ============================
// Shared-S: per i, S_i[k,b] = sum_j T[k,i,j] c[b,j] via 2-term MFMA (T bf16-hi, c hi/lo;
// jh splits the j/K dim); bil_v[k,b] += a_v[b,i] * S_i (exact f32 scalars, R12 form).
// TWO i per barrier-step: reads bufs i0&3,(i0+1)&3 while staging (i0+2)&3,(i0+3)&3.
// MODE 0: {a1,ar} = ntn({e1,er}, p, T1) -> TILE_AB
// MODE 1: c2 = ntn(p, e2, T2)           -> TILE_C
// MODE 2: {u,ur} = ntn({a1,ar}, c2, T3) -> global out
template<int MODE>
__device__ void pass_run(u8* sm, const u8* __restrict__ ws,
                         const float* __restrict__ gC, const float* __restrict__ gA0,
                         const float* __restrict__ gA1,
                         const float* __restrict__ bias, float* __restrict__ outg,
                         int B0, int w, int kt, int jh, int l, int lr, int lq, int tid)
{
    constexpr int NV = (MODE == 1) ? 1 : 2;
    const u8* tws = ws + WS_T(MODE);

    // prologue: first slice pair in flight under the ff work
    stage_slice(sm, tws,                    0, w, l);
    stage_slice(sm, tws + (size_t)1 * 8192, 1, w, l);

    // ---------- c-side B-frags for the i-loop (own jh half, static) ----------
    short8v Bh[4], Bl[4];
#pragma unroll
    for (int nt = 0; nt < 4; ++nt) {
        const int b = nt * 16 + lr;
        Frag2 f;
        if (MODE < 2) f = split8(gC + (size_t)(B0 + b) * 64 + jh * 32 + lq * 8);
        else          f = gather_c(sm, b, jh * 32 + lq * 8);
        Bh[nt] = f.h; Bl[nt] = f.l;
    }

    // ---------- ff init (jh-split), R12 form ----------
    f32x4 bil[NV][4];
    {
        const u16* Wp = (const u16*)(ws + WS_W);
        if (jh == 0) {                              // W2 . c + bias (shared by the pair)
            short8v w2h[2], w2l[2];
#pragma unroll
            for (int h = 0; h < 2; ++h) {
                const int off = (kt * 16 + lr) * 64 + h * 32 + lq * 8;
                w2h[h] = *(const short8v*)(Wp + 8192 + off);
                w2l[h] = *(const short8v*)(Wp + 12288 + off);
            }
            const f32x4 bv4 = *(const f32x4*)(bias + kt * 16 + lq * 4);
#pragma unroll
            for (int nt = 0; nt < 4; ++nt) {
                const int b = nt * 16 + lr;
                f32x4 s = {0.f, 0.f, 0.f, 0.f};
#pragma unroll
                for (int h = 0; h < 2; ++h) {
                    Frag2 fc;
                    if (MODE < 2) fc = split8(gC + (size_t)(B0 + b) * 64 + h * 32 + lq * 8);
                    else          fc = gather_c(sm, b, h * 32 + lq * 8);
                    s = mfma3(w2h[h], w2l[h], fc.h, fc.l, s);
                }
#pragma unroll
                for (int v = 0; v < NV; ++v)
#pragma unroll
                for (int rg = 0; rg < 4; ++rg) bil[v][nt][rg] = s[rg] + bv4[rg];
            }
        } else {                                    // W1 . a_v
            short8v w1h[2], w1l[2];
#pragma unroll
            for (int h = 0; h < 2; ++h) {
                const int off = (kt * 16 + lr) * 64 + h * 32 + lq * 8;
                w1h[h] = *(const short8v*)(Wp + off);
                w1l[h] = *(const short8v*)(Wp + 4096 + off);
            }
#pragma unroll
            for (int nt = 0; nt < 4; ++nt) {
                const int b = nt * 16 + lr;
                f32x4 sv0 = {0.f, 0.f, 0.f, 0.f};
                f32x4 sv1 = {0.f, 0.f, 0.f, 0.f};
#pragma unroll
                for (int h = 0; h < 2; ++h) {
                    Frag2 fa, fb;
                    if (MODE == 0) {
                        fa = split8(gA0 + (size_t)(B0 + b) * 64 + h * 32 + lq * 8);
                        fb = split8(gA1 + (size_t)(B0 + b) * 64 + h * 32 + lq * 8);
                    } else if (MODE == 1) {
                        fa = split8(gA0 + (size_t)(B0 + b) * 64 + h * 32 + lq * 8);
                    } else {
                        gather_ab(sm, b, h * 32 + lq * 8, fa, fb);
                    }
                    sv0 = mfma3(w1h[h], w1l[h], fa.h, fa.l, sv0);
                    if (NV == 2) sv1 = mfma3(w1h[h], w1l[h], fb.h, fb.l, sv1);
                }
                bil[0][nt] = sv0;
                if (NV == 2) bil[1][nt] = sv1;
            }
        }
    }

    // ---------- i-loop: 2 slices per barrier-step, unpaired R12 accumulate ----------
    const int tswz = kt * 2048 + lr * 128 + (((jh * 4 + lq) ^ (lr & 7)) << 4);
    const f32x4 ZERO4 = {0.f, 0.f, 0.f, 0.f};       // persistent MFMA C-seed

#define STEP2(I0, DOSTG) do {                                                              \
    f32x2 sva[4], svb[4];                                                                  \
    _Pragma("unroll") for (int nt = 0; nt < 4; ++nt) {                                     \
        if (MODE == 1) {                                                                   \
            sva[nt].x = *(const float*)(sm + TILE_C + (I0) * 256 + nt * 64 + lr * 4);      \
            svb[nt].x = *(const float*)(sm + TILE_C + ((I0) + 1) * 256 + nt * 64 + lr * 4);\
        } else {                                                                           \
            sva[nt] = *(const f32x2*)(sm + TILE_AB + (I0) * 512 + nt * 128 + lr * 8);      \
            svb[nt] = *(const f32x2*)(sm + TILE_AB + ((I0) + 1) * 512 + nt * 128 + lr * 8);\
        }                                                                                  \
    }                                                                                      \
    asm volatile("s_waitcnt vmcnt(0)" ::: "memory");                                       \
    __builtin_amdgcn_sched_barrier(0);                                                     \
    __builtin_amdgcn_s_barrier();                                                          \
    __builtin_amdgcn_sched_barrier(0);                                                     \
    if (DOSTG) {                                                                           \
        stage_slice(sm, tws + (size_t)((I0) + 2) * 8192, ((I0) + 2) & 3, w, l);            \
        stage_slice(sm, tws + (size_t)((I0) + 3) * 8192, ((I0) + 3) & 3, w, l);            \
    }                                                                                      \
    const short8v Tha_ = *(const short8v*)(sm + ((I0) & 3) * 8192 + tswz);                 \
    f32x4 Sa_[4];                                                                          \
    __builtin_amdgcn_s_setprio(1);                                                         \
    _Pragma("unroll") for (int nt = 0; nt < 4; ++nt) {                                     \
        f32x4 z_ = MFMA16(Tha_, Bh[nt], ZERO4, 0, 0, 0);                                   \
        Sa_[nt] = MFMA16(Tha_, Bl[nt], z_, 0, 0, 0);                                       \
    }                                                                                      \
    __builtin_amdgcn_s_setprio(0);                                                         \
    _Pragma("unroll") for (int nt = 0; nt < 4; ++nt)                                       \
    _Pragma("unroll") for (int rg = 0; rg < 4; ++rg) {                                     \
        bil[0][nt][rg] += sva[nt].x * Sa_[nt][rg];                                         \
        if (NV == 2) bil[1][nt][rg] += sva[nt].y * Sa_[nt][rg];                            \
    }                                                                                      \
    const short8v Thb_ = *(const short8v*)(sm + (((I0) + 1) & 3) * 8192 + tswz);           \
    f32x4 Sb_[4];                                                                          \
    __builtin_amdgcn_s_setprio(1);                                                         \
    _Pragma("unroll") for (int nt = 0; nt < 4; ++nt) {                                     \
        f32x4 z_ = MFMA16(Thb_, Bh[nt], ZERO4, 0, 0, 0);                                   \
        Sb_[nt] = MFMA16(Thb_, Bl[nt], z_, 0, 0, 0);                                       \
    }                                                                                      \
    __builtin_amdgcn_s_setprio(0);                                                         \
    _Pragma("unroll") for (int nt = 0; nt < 4; ++nt)                                       \
    _Pragma("unroll") for (int rg = 0; rg < 4; ++rg) {                                     \
        bil[0][nt][rg] += svb[nt].x * Sb_[nt][rg];                                         \
        if (NV == 2) bil[1][nt][rg] += svb[nt].y * Sb_[nt][rg];                            \
    }                                                                                      \
} while (0)

#pragma unroll 2
    for (int s = 0; s < 31; ++s) STEP2(s * 2, true);
    STEP2(62, false);
#undef STEP2

    // ---------- jh merge (once per pass) + tanh + store (R12 verbatim) ----------
    __syncthreads();                                // stage bufs dead -> PRE
    float* PRE = (float*)sm;                        // [NV][64 k][64 b] f32
    if (jh == 1) {
#pragma unroll
        for (int v = 0; v < NV; ++v)
#pragma unroll
        for (int nt = 0; nt < 4; ++nt)
#pragma unroll
        for (int rg = 0; rg < 4; ++rg)
            PRE[v * 4096 + (kt * 16 + lq * 4 + rg) * 64 + nt * 16 + lr] = bil[v][nt][rg];
    }
    __syncthreads();

    if (MODE == 0) {
        if (jh == 0) {
#pragma unroll
            for (int nt = 0; nt < 4; ++nt) {
                const int b = nt * 16 + lr;
#pragma unroll
                for (int rg = 0; rg < 4; ++rg) {
                    const int k = kt * 16 + lq * 4 + rg;
                    f32x2 o;
                    o.x = tanhf(bil[0][nt][rg] + PRE[k * 64 + b]);
                    o.y = tanhf(bil[1][nt][rg] + PRE[4096 + k * 64 + b]);
                    *(f32x2*)(sm + TILE_AB + (size_t)k * 512 + b * 8) = o;
                }
            }
        }
        __syncthreads();
    } else if (MODE == 1) {
        if (jh == 0) {
#pragma unroll
            for (int nt = 0; nt < 4; ++nt) {
                const int b = nt * 16 + lr;
#pragma unroll
                for (int rg = 0; rg < 4; ++rg) {
                    const int k = kt * 16 + lq * 4 + rg;
                    *(float*)(sm + TILE_C + k * 256 + b * 4) =
                        tanhf(bil[0][nt][rg] + PRE[k * 64 + b]);
                }
            }
        }
        __syncthreads();
    } else {
        f32x2 ures[4][4];
        if (jh == 0) {
#pragma unroll
            for (int nt = 0; nt < 4; ++nt) {
                const int b = nt * 16 + lr;
#pragma unroll
                for (int rg = 0; rg < 4; ++rg) {
                    const int k = kt * 16 + lq * 4 + rg;
                    ures[nt][rg].x = tanhf(bil[0][nt][rg] + PRE[k * 64 + b]);
                    ures[nt][rg].y = tanhf(bil[1][nt][rg] + PRE[4096 + k * 64 + b]);
                }
            }
        }
        __syncthreads();                            // PRE reads done -> OSTG may overwrite
        if (jh == 0) {
#pragma unroll
            for (int nt = 0; nt < 4; ++nt) {
                const int b = nt * 16 + lr;
#pragma unroll
                for (int rg = 0; rg < 4; ++rg) {
                    const int k = kt * 16 + lq * 4 + rg;
                    *(f32x2*)(sm + b * 512 + (((k ^ b) & 63) << 3)) = ures[nt][rg];
                }
            }
        }
        __syncthreads();
        const int bq = tid >> 3, t = tid & 7;       // coalesced 64B per thread
        float o[16];
#pragma unroll
        for (int kk = 0; kk < 8; ++kk) {
            const int k = t * 8 + kk;
            const f32x2 pr = *(const f32x2*)(sm + bq * 512 + (((k ^ bq) & 63) << 3));
            o[kk * 2] = pr.x; o[kk * 2 + 1] = pr.y;
        }
        float* dst = outg + (size_t)(B0 + bq) * 128 + t * 16;
#pragma unroll
        for (int q = 0; q < 4; ++q) *(f32x4*)(dst + q * 4) = *(const f32x4*)(o + q * 4);
    }
}

__global__ __launch_bounds__(512, 4)
void ntn_main(const float* __restrict__ e1, const float* __restrict__ p,
              const float* __restrict__ e2, const float* __restrict__ er,
              const float* __restrict__ bias, const u8* __restrict__ ws,
              float* __restrict__ out)
{
    __shared__ __align__(16) u8 sm[SMB];
    const int tid = threadIdx.x;
    const int l = tid & 63;
    const int w = __builtin_amdgcn_readfirstlane(tid >> 6);
    const int kt = w & 3, jh = w >> 2;
    const int lr = l & 15, lq = l >> 4;
    const int B0 = blockIdx.x * 64;

    // fill tiles: AB = (e1, er) interleaved [f][b], C = p mono [f][b]
    {
        const int b = tid >> 3, f0 = (tid & 7) * 8;
        const size_t g = (size_t)(B0 + b) * 64 + f0;
        const f32x4 a0 = *(const f32x4*)(e1 + g), a1v = *(const f32x4*)(e1 + g + 4);
        const f32x4 r0 = *(const f32x4*)(er + g), r1v = *(const f32x4*)(er + g + 4);
        const f32x4 p0 = *(const f32x4*)(p + g),  p1v = *(const f32x4*)(p + g + 4);
#pragma unroll
        for (int e = 0; e < 4; ++e) {
            f32x2 v0; v0.x = a0[e]; v0.y = r0[e];
            *(f32x2*)(sm + TILE_AB + (size_t)(f0 + e) * 512 + b * 8) = v0;
            f32x2 v1; v1.x = a1v[e]; v1.y = r1v[e];
            *(f32x2*)(sm + TILE_AB + (size_t)(f0 + 4 + e) * 512 + b * 8) = v1;
            *(float*)(sm + TILE_C + (f0 + e) * 256 + b * 4) = p0[e];
            *(float*)(sm + TILE_C + (f0 + 4 + e) * 256 + b * 4) = p1v[e];
        }
    }
    __syncthreads();

    pass_run<0>(sm, ws, p,  e1, er,      bias, nullptr, B0, w, kt, jh, l, lr, lq, tid);
    pass_run<1>(sm, ws, e2, p,  nullptr, bias, nullptr, B0, w, kt, jh, l, lr, lq, tid);
    pass_run<2>(sm, ws, nullptr, nullptr, nullptr, bias, out, B0, w, kt, jh, l, lr, lq, tid);
}

extern "C" void kernel_launch(void* const* d_in, const int* in_sizes, int n_in,
                              void* d_out, int out_size, void* d_ws, size_t ws_size,
                              hipStream_t stream) {
    const float* e1   = (const float*)d_in[0];
    const float* p    = (const float*)d_in[1];
    const float* e2   = (const float*)d_in[2];
    const float* er   = (const float*)d_in[3];
    const float* T1   = (const float*)d_in[4];
    const float* T2   = (const float*)d_in[5];
    const float* T3   = (const float*)d_in[6];
    const float* W    = (const float*)d_in[7];
    const float* bias = (const float*)d_in[8];

    u8* ws = (u8*)d_ws;
    hipLaunchKernelGGL(presplit_kernel, dim3(3136), dim3(256), 0, stream, T1, T2, T3, W, ws);
    hipLaunchKernelGGL(ntn_main, dim3(BATCH / 64), dim3(512), 0, stream,
                       e1, p, e2, er, bias, (const u8*)ws, (float*)d_out);
}